// Round 9
// baseline (363.269 us; speedup 1.0000x reference)
//
#include <hip/hip_runtime.h>
#include <cmath>

#define HW   256
#define NPIX 65536       // 256*256
#define NP   65600       // padded channel stride for yr (64-entry zero pad)
#define CIN  64
#define C2   340
#define HID  170

// g workspace: per row, 6 chunks x 16384 B (byte-image of the old LDS tile);
// per batch 256 rows.
#define GROWB   98304
#define GBATCH  (256 * (size_t)GROWB)   // 25,165,824 B

typedef _Float16 f16x8 __attribute__((ext_vector_type(8)));
typedef float    f32x4 __attribute__((ext_vector_type(4)));
typedef unsigned int u32;

// Orthonormal DCT-II basis for n=8 as compile-time constants.
#define A0 0.35355339059327373f
#define A1 0.49039264020161522f
#define A2 0.46193976625564337f
#define A3 0.41573480615127262f
#define A4 0.35355339059327379f
#define A5 0.27778511650980114f
#define A6 0.19134171618254492f
#define A7 0.09754516100806417f

// 8-point orthonormal DCT-II via even/odd butterfly: y = M v.  36 ops vs 64.
__device__ __forceinline__ void dct8(const float v[8], float y[8]) {
    const float u0 = v[0] + v[7], u1 = v[1] + v[6];
    const float u2 = v[2] + v[5], u3 = v[3] + v[4];
    const float w0 = v[0] - v[7], w1 = v[1] - v[6];
    const float w2 = v[2] - v[5], w3 = v[3] - v[4];
    const float s0 = u0 + u3, s1 = u1 + u2;
    const float t0 = u0 - u3, t1 = u1 - u2;
    y[0] = A0 * (s0 + s1);
    y[4] = A4 * (s0 - s1);
    y[2] = fmaf(A2, t0,  A6 * t1);
    y[6] = fmaf(A6, t0, -A2 * t1);
    y[1] = fmaf(A1, w0, fmaf( A3, w1, fmaf( A5, w2,  A7 * w3)));
    y[3] = fmaf(A3, w0, fmaf(-A7, w1, fmaf(-A1, w2, -A5 * w3)));
    y[5] = fmaf(A5, w0, fmaf(-A1, w1, fmaf( A7, w2,  A3 * w3)));
    y[7] = fmaf(A7, w0, fmaf(-A5, w1, fmaf( A3, w2, -A1 * w3)));
}

// 8-point inverse (x = M^T y), same butterfly structure reversed.  36 ops.
__device__ __forceinline__ void idct8(const float y[8], float x[8]) {
    const float sa = fmaf( A4, y[4], A0 * y[0]);
    const float sb = fmaf(-A4, y[4], A0 * y[0]);
    const float c0 = fmaf( A2, y[2],  A6 * y[6]);
    const float c1 = fmaf( A6, y[2], -A2 * y[6]);
    const float e0 = sa + c0, e3 = sa - c0;
    const float e1 = sb + c1, e2 = sb - c1;
    const float o0 = fmaf(A1, y[1], fmaf( A3, y[3], fmaf( A5, y[5],  A7 * y[7])));
    const float o1 = fmaf(A3, y[1], fmaf(-A7, y[3], fmaf(-A1, y[5], -A5 * y[7])));
    const float o2 = fmaf(A5, y[1], fmaf(-A1, y[3], fmaf( A7, y[5],  A3 * y[7])));
    const float o3 = fmaf(A7, y[1], fmaf(-A5, y[3], fmaf( A3, y[5], -A1 * y[7])));
    x[0] = e0 + o0; x[7] = e0 - o0;
    x[1] = e1 + o1; x[6] = e1 - o1;
    x[2] = e2 + o2; x[5] = e2 - o2;
    x[3] = e3 + o3; x[4] = e3 - o3;
}

// Rotated Csh column: logical (patch,within) at row, channel ocl ->
// physical column. Breaks the 8-way same-bank pattern of straight layout.
__device__ __forceinline__ int pcolrot(int blk, int row, int ocl) {
    return ((blk + row + (ocl >> 2)) & 3) << 3;
}

// ---------------------------------------------------------------------------
// Prep: WinH fp16 [352][64] (rows >=340 zero), WoutKH fp16 [64][192]
// (WoutKH[o][h] = Wout[o][h], h>=170 zero).
// ---------------------------------------------------------------------------
__global__ __launch_bounds__(256) void kprep(const float* __restrict__ Win,
                                             const float* __restrict__ Wout,
                                             _Float16* __restrict__ WinH,
                                             _Float16* __restrict__ WoutKH)
{
    const int i = blockIdx.x * 256 + threadIdx.x;
    if (i < 352 * 64) WinH[i] = (i < C2 * 64) ? (_Float16)Win[i] : (_Float16)0.f;
    if (i < 64 * 192) {
        const int o = i / 192, h = i - o * 192;
        WoutKH[i] = (h < HID) ? (_Float16)Wout[o * HID + h] : (_Float16)0.f;
    }
}

// ---------------------------------------------------------------------------
// Kernel A (r4 restructure): forward 2D DCT moved to the cin side (commutes
// with the 1x1 projection).  (byte-identical to r4 — untouched)
// ---------------------------------------------------------------------------
__global__ __launch_bounds__(256) void kA(
    const float* __restrict__ x,        // [nb][64][256][256]
    const _Float16* __restrict__ WinH,  // [352][64] fp16 (zero-padded)
    const float* __restrict__ quant,    // [340][8][8]
    _Float16* __restrict__ yr)          // [nb][340][NP] fp16
{
    const int tid  = threadIdx.x;
    const int tile = blockIdx.x;
    const int bb   = blockIdx.y;
    const int ty = tile >> 3, tx = tile & 7;     // ty 0..31, tx 0..7
    const int y0 = ty * 8,    x0 = tx * 32;
    const int wv = tid >> 6;
    const int l15 = tid & 15, quad = (tid & 63) >> 4;

    __shared__ float csh[32 * 264];     // 33792 B

    // Zero yr's per-channel pad region for this batch (tile 0 blocks only).
    if (tile == 0) {
        const f16x8 z = {(_Float16)0.f,(_Float16)0.f,(_Float16)0.f,(_Float16)0.f,
                         (_Float16)0.f,(_Float16)0.f,(_Float16)0.f,(_Float16)0.f};
#pragma unroll 1
        for (int it = 0; it < 11; ++it) {
            const int idx = tid + it * 256;            // 2720 groups of 8
            if (idx < C2 * 8) {
                const int oc = idx >> 3, sub = idx & 7;
                *(f16x8*)&yr[(size_t)(bb * C2 + oc) * NP + NPIX + sub * 8] = z;
            }
        }
    }

    // Transform-phase roles
    const int ch  = tid >> 5;             // 0..7
    const int pat = (tid >> 3) & 3;       // 0..3 (horizontal patch)
    const int lan = tid & 7;              // 0..7

    const float* xb = x + (size_t)bb * (CIN * NPIX);

    // ---- Prologue: 2D DCT of x -> fp16 A-fragments (2 halves of 32 cin) ----
    f16x8 af0[4], af1[4];
#pragma unroll
    for (int hh = 0; hh < 2; ++hh) {
#pragma unroll
        for (int di = 0; di < 4; ++di) {
            const int ci = ch + 8 * di;
            const float* gp = xb + (size_t)(hh * 32 + ci) * NPIX
                              + (y0 + lan) * HW + x0 + pat * 8;
            float v[8], o[8];
            *(f32x4*)&v[0] = *(const f32x4*)gp;
            *(f32x4*)&v[4] = *(const f32x4*)(gp + 4);
            dct8(v, o);
            float* rowp = &csh[ci * 264 + lan * 32 + pcolrot(pat, lan, ci)];
            *(f32x4*)rowp       = *(const f32x4*)&o[0];
            *(f32x4*)(rowp + 4) = *(const f32x4*)&o[4];
        }
        __syncthreads();
#pragma unroll
        for (int di = 0; di < 4; ++di) {
            const int ci = ch + 8 * di;
            float v[8], o[8];
#pragma unroll
            for (int i = 0; i < 8; ++i)
                v[i] = csh[ci * 264 + i * 32 + pcolrot(pat, i, ci) + lan];
            dct8(v, o);
#pragma unroll
            for (int i = 0; i < 8; ++i)
                csh[ci * 264 + i * 32 + pcolrot(pat, i, ci) + lan] = o[i];
        }
        __syncthreads();
#pragma unroll
        for (int tt = 0; tt < 4; ++tt) {
            const int apx = (wv * 4 + tt) * 16 + l15;
            const int prw = apx >> 5;             // vertical freq i (0..7)
            const int pc  = apx & 31;
            const int pp  = pc >> 3, pl = pc & 7; // patch, horizontal freq j
            union { _Float16 h[8]; f16x8 v; } pk;
#pragma unroll
            for (int e = 0; e < 8; ++e) {
                const int ci = quad * 8 + e;
                pk.h[e] = (_Float16)csh[ci * 264 + prw * 32
                                        + pcolrot(pp, prw, ci) + pl];
            }
            if (hh == 0) af0[tt] = pk.v; else af1[tt] = pk.v;
        }
        __syncthreads();
    }

#pragma unroll 1
    for (int sc = 0; sc < 11; ++sc) {
        const int oc0 = sc * 32;

        // ---- MFMA projection (DCT domain) + fused quant -> csh ----
#pragma unroll
        for (int g2 = 0; g2 < 2; ++g2) {
            const int ocb = oc0 + g2 * 16 + l15;           // WinH zero-padded
            const f16x8 b0 = *(const f16x8*)(WinH + ocb * 64 + quad * 8);
            const f16x8 b1 = *(const f16x8*)(WinH + ocb * 64 + 32 + quad * 8);
            const int ocl = g2 * 16 + l15;
            int ocq = oc0 + ocl; if (ocq > C2 - 1) ocq = C2 - 1;
            const float* qbase = quant + ocq * 64 + (quad & 1) * 4;
#pragma unroll
            for (int tt = 0; tt < 4; ++tt) {
                const int tile16 = wv * 4 + tt;
                f32x4 acc = {0.f, 0.f, 0.f, 0.f};
                acc = __builtin_amdgcn_mfma_f32_16x16x32_f16(af0[tt], b0, acc, 0, 0, 0);
                acc = __builtin_amdgcn_mfma_f32_16x16x32_f16(af1[tt], b1, acc, 0, 0, 0);
                const int prow = tile16 >> 1;                  // freq row i
                const int blk  = ((tile16 & 1) << 1) | (quad >> 1);
                const f32x4 qv = *(const f32x4*)(qbase + prow * 8);
                acc *= qv;
                *(f32x4*)&csh[ocl * 264 + prow * 32 + pcolrot(blk, prow, ocl)
                              + (quad & 1) * 4] = acc;
            }
        }
        __syncthreads();

        // ---- Col-IDCT (vertical) ----
#pragma unroll
        for (int di = 0; di < 4; ++di) {
            const int ocl = ch + 8 * di;
            float v[8], e8[8];
#pragma unroll
            for (int i = 0; i < 8; ++i)
                v[i] = csh[ocl * 264 + i * 32 + pcolrot(pat, i, ocl) + lan];
            idct8(v, e8);
#pragma unroll
            for (int i = 0; i < 8; ++i)
                csh[ocl * 264 + i * 32 + pcolrot(pat, i, ocl) + lan] = e8[i];
        }
        __syncthreads();

        // ---- Row-IDCT -> global fp16, 64B full sectors ----
#pragma unroll
        for (int di = 0; di < 4; ++di) {
            const int ocl = ch + 8 * di;
            const int oc  = oc0 + ocl;
            const float* rowp = &csh[ocl * 264 + lan * 32 + pcolrot(pat, lan, ocl)];
            float v[8], e8[8];
            *(f32x4*)&v[0] = *(const f32x4*)rowp;
            *(f32x4*)&v[4] = *(const f32x4*)(rowp + 4);
            idct8(v, e8);
            union { _Float16 h[8]; f16x8 f; } u;
#pragma unroll
            for (int q = 0; q < 8; ++q) u.h[q] = (_Float16)e8[q];
            if (oc < C2) {
                f16x8* dst = (f16x8*)(yr + (size_t)(bb * C2 + oc) * NP
                                      + (y0 + lan) * HW + x0 + pat * 8);
                *dst = u.f;
            }
        }
        __syncthreads();
    }
}

// ---------------------------------------------------------------------------
// Kernel G (r8 split): depthwise 3x3 + exact gelu gate only.  Conv math is
// byte-identical to the proven r5 kB.  Output pk tiles go straight to the
// g workspace as the byte-image of the old LDS tile (same swizzled offsets),
// so kB2 can read MFMA A-fragments with the old reader formula.
// No acc, no LDS, no barriers -> low VGPR -> 4 waves/SIMD (2x old hiding).
// Grid (512, nb): blockIdx.x&255 = row, >>8 = chunk-half (3 chunks each).
// ---------------------------------------------------------------------------
__global__ __launch_bounds__(256, 4) void kG(
    const _Float16* __restrict__ yr,      // [nb][340][NP] fp16
    const float* __restrict__ Wdw,        // [340][9]
    _Float16* __restrict__ g)             // [nb][256 rows][6 chunks][16384 B]
{
    const int tid  = threadIdx.x;
    const int bb   = blockIdx.y;
    const int idf  = blockIdx.x;                        // 0..511
    const int id   = idf & 255;
    const int half = idf >> 8;                          // 0..1
    const int row  = ((id & 7) << 5) | (id >> 3);       // XCD strip swizzle
    const int wv   = tid >> 6;
    const int L    = tid & 63;

    const char* ybase = (const char*)(yr + (size_t)bb * C2 * NP) - 16;

    unsigned boff[3];
#pragma unroll
    for (int rr = 0; rr < 3; ++rr) {
        const int trow = row + rr - 1;
        boff[rr] = ((unsigned)trow < (unsigned)HW)
                 ? (unsigned)(trow * (HW * 2) + 8 * L + 12)
                 : (unsigned)(NPIX * 2 + 16);
    }
    const float mL = (L == 0)  ? 0.f : 1.f;   // zero col -1  (element 1)
    const float mR = (L == 63) ? 0.f : 1.f;   // zero col 256 (element 6)

    // Per-lane g byte address (same formula as the old LDS gpc).
    char* gbase = (char*)g + (size_t)bb * GBATCH + (size_t)row * GROWB
                + L * 256 + ((wv ^ (L & 3)) << 4);

#pragma unroll 1
    for (int chunk = half * 3; chunk < half * 3 + 3; ++chunk) {
        const int hc = chunk * 32;

        union { _Float16 h[8]; f16x8 v; } pk0, pk1, pk2, pk3;
#pragma unroll
        for (int j = 0; j < 8; ++j) {
            const int h = hc + wv * 8 + j;          // wave-uniform
            float gg0 = 0.f, gg1 = 0.f, gg2 = 0.f, gg3 = 0.f;
            if (h < HID) {
                const char* p1 = ybase + (size_t)h * (NP * 2);
                const char* p2 = p1 + (size_t)HID * (NP * 2);
                const float* w1 = Wdw + h * 9;
                const float* w2 = w1 + HID * 9;
                float s1[4] = {0.f, 0.f, 0.f, 0.f};
                float s2[4] = {0.f, 0.f, 0.f, 0.f};
#pragma unroll
                for (int rr = 0; rr < 3; ++rr) {
                    f16x8 a1, a2;
                    __builtin_memcpy(&a1, p1 + boff[rr], 16);
                    __builtin_memcpy(&a2, p2 + boff[rr], 16);
                    float v1[8], v2[8];
#pragma unroll
                    for (int e = 1; e <= 6; ++e) {
                        v1[e] = (float)a1[e];
                        v2[e] = (float)a2[e];
                    }
                    v1[1] *= mL; v2[1] *= mL;
                    v1[6] *= mR; v2[6] *= mR;
                    const float wa = w1[rr*3+0], wb = w1[rr*3+1], wc = w1[rr*3+2];
                    const float wd = w2[rr*3+0], we = w2[rr*3+1], wf = w2[rr*3+2];
#pragma unroll
                    for (int i = 0; i < 4; ++i) {
                        s1[i] = fmaf(v1[i+1], wa, s1[i]);
                        s1[i] = fmaf(v1[i+2], wb, s1[i]);
                        s1[i] = fmaf(v1[i+3], wc, s1[i]);
                        s2[i] = fmaf(v2[i+1], wd, s2[i]);
                        s2[i] = fmaf(v2[i+2], we, s2[i]);
                        s2[i] = fmaf(v2[i+3], wf, s2[i]);
                    }
                }
                const float KC = 0.70710678118654752f;
                gg0 = 0.5f * s1[0] * (1.f + erff(s1[0] * KC)) * s2[0];
                gg1 = 0.5f * s1[1] * (1.f + erff(s1[1] * KC)) * s2[1];
                gg2 = 0.5f * s1[2] * (1.f + erff(s1[2] * KC)) * s2[2];
                gg3 = 0.5f * s1[3] * (1.f + erff(s1[3] * KC)) * s2[3];
            }
            pk0.h[j] = (_Float16)gg0;
            pk1.h[j] = (_Float16)gg1;
            pk2.h[j] = (_Float16)gg2;
            pk3.h[j] = (_Float16)gg3;
        }
        char* gp = gbase + chunk * 16384;
        *(f16x8*)(gp      ) = pk0.v;   // px 4L+0
        *(f16x8*)(gp +  64) = pk1.v;   // px 4L+1
        *(f16x8*)(gp + 128) = pk2.v;   // px 4L+2
        *(f16x8*)(gp + 192) = pk3.v;   // px 4L+3
    }
}

// ---------------------------------------------------------------------------
// Kernel B2 (r8 split): project_out GEMM + epilogue.  A-fragments read
// directly from the g byte-image with the old LDS-reader formula (L2/L3-hot).
// No conv state -> ~110 total regs -> 4 waves/SIMD; no barriers in the loop.
// ---------------------------------------------------------------------------
__global__ __launch_bounds__(256, 4) void kB2(
    const _Float16* __restrict__ g,       // [nb][256][6][16384 B]
    const _Float16* __restrict__ WoutKH,  // [64][192] fp16 (zero-padded)
    float* __restrict__ out)              // [nb][64][256][256]
{
    const int tid = threadIdx.x;
    const int bb  = blockIdx.y;
    const int id  = blockIdx.x;                         // 0..255
    const int row = ((id & 7) << 5) | (id >> 3);        // XCD strip swizzle
    const int wv  = tid >> 6;
    const int l15 = tid & 15, quad = (tid & 63) >> 4;

    __shared__ float tsh[16 * 257];      // 16448 B epilogue transpose

    const char* gb = (const char*)g + (size_t)bb * GBATCH + (size_t)row * GROWB;
    const int slotoff = (quad ^ ((l15 >> 2) & 3)) << 4;

    f32x4 acc[4][4];   // [px-tile tt][oc-group p]
#pragma unroll
    for (int a = 0; a < 4; ++a)
#pragma unroll
        for (int b = 0; b < 4; ++b) acc[a][b] = (f32x4){0.f, 0.f, 0.f, 0.f};

#pragma unroll 1
    for (int chunk = 0; chunk < 6; ++chunk) {
        const int hc = chunk * 32;
        const char* gc = gb + chunk * 16384;

        f16x8 av[4];
#pragma unroll
        for (int tt = 0; tt < 4; ++tt) {
            const int apx = (wv * 4 + tt) * 16 + l15;
            __builtin_memcpy(&av[tt], gc + apx * 64 + slotoff, 16);
        }
#pragma unroll
        for (int tt = 0; tt < 4; ++tt) {
#pragma unroll
            for (int p = 0; p < 4; ++p) {
                const f16x8 b = *(const f16x8*)(WoutKH + (p * 16 + l15) * 192 + hc + quad * 8);
                acc[tt][p] = __builtin_amdgcn_mfma_f32_16x16x32_f16(av[tt], b, acc[tt][p], 0, 0, 0);
            }
        }
    }

    // ---- Epilogue: LDS transpose -> coalesced stores (static acc idx) ----
    float* ob = out + (size_t)bb * CIN * NPIX + row * HW + tid;
#pragma unroll
    for (int p = 0; p < 4; ++p) {
#pragma unroll
        for (int tt = 0; tt < 4; ++tt) {
            const int px = (wv * 4 + tt) * 16 + quad * 4;
#pragma unroll
            for (int reg = 0; reg < 4; ++reg)
                tsh[l15 * 257 + px + reg] = acc[tt][p][reg];
        }
        __syncthreads();
#pragma unroll
        for (int o2 = 0; o2 < 16; ++o2)
            ob[(size_t)(p * 16 + o2) * NPIX] = tsh[o2 * 257 + tid];
        __syncthreads();
    }
}

extern "C" void kernel_launch(void* const* d_in, const int* in_sizes, int n_in,
                              void* d_out, int out_size, void* d_ws, size_t ws_size,
                              hipStream_t stream)
{
    const float* x     = (const float*)d_in[0];
    const float* Win   = (const float*)d_in[1];
    const float* Wdw   = (const float*)d_in[2];
    const float* quant = (const float*)d_in[3];
    const float* Wout  = (const float*)d_in[4];
    float* out = (float*)d_out;

    // ws: WinH [0,45056) ; WoutKH [45056,69632) ; yr at 69632 ; g after yr.
    _Float16* WinH   = (_Float16*)d_ws;
    _Float16* WoutKH = (_Float16*)((char*)d_ws + 45056);
    _Float16* yrbuf  = (_Float16*)((char*)d_ws + 69632);

    const size_t yrB  = (size_t)C2 * NP * sizeof(_Float16);  // 44.6 MB
    const size_t gB   = GBATCH;                              // 25.2 MB
    const size_t perBatch = yrB + gB;                        // 69.8 MB
    const size_t head = 69632;
    const size_t avail = ws_size > head ? ws_size - head : 0;
    int nb = 1;
    if (avail >= 4 * perBatch)      nb = 4;
    else if (avail >= 2 * perBatch) nb = 2;

    _Float16* gbuf = (_Float16*)((char*)d_ws + head + (size_t)nb * yrB);

    kprep<<<88, 256, 0, stream>>>(Win, Wout, WinH, WoutKH);

    for (int b0 = 0; b0 < 4; b0 += nb) {
        dim3 gridA(256, nb), gridG(512, nb), gridB(256, nb);
        kA<<<gridA, 256, 0, stream>>>(x + (size_t)b0 * CIN * NPIX, WinH, quant, yrbuf);
        kG<<<gridG, 256, 0, stream>>>(yrbuf, Wdw, gbuf);
        kB2<<<gridB, 256, 0, stream>>>(gbuf, WoutKH, out + (size_t)b0 * CIN * NPIX);
    }
}

// Round 10
// 314.361 us; speedup vs baseline: 1.1556x; 1.1556x over previous
//
#include <hip/hip_runtime.h>
#include <cmath>

#define HW   256
#define NPIX 65536       // 256*256
#define NP   65600       // padded channel stride for yr (64-entry zero pad)
#define CIN  64
#define C2   340
#define HID  170

typedef _Float16 f16x8 __attribute__((ext_vector_type(8)));
typedef _Float16 f16x4v __attribute__((ext_vector_type(4)));
typedef float    f32x4 __attribute__((ext_vector_type(4)));
typedef unsigned int u32;

// Orthonormal DCT-II basis for n=8 as compile-time constants.
#define A0 0.35355339059327373f
#define A1 0.49039264020161522f
#define A2 0.46193976625564337f
#define A3 0.41573480615127262f
#define A4 0.35355339059327379f
#define A5 0.27778511650980114f
#define A6 0.19134171618254492f
#define A7 0.09754516100806417f

// 8-point orthonormal DCT-II via even/odd butterfly: y = M v.  36 ops vs 64.
__device__ __forceinline__ void dct8(const float v[8], float y[8]) {
    const float u0 = v[0] + v[7], u1 = v[1] + v[6];
    const float u2 = v[2] + v[5], u3 = v[3] + v[4];
    const float w0 = v[0] - v[7], w1 = v[1] - v[6];
    const float w2 = v[2] - v[5], w3 = v[3] - v[4];
    const float s0 = u0 + u3, s1 = u1 + u2;
    const float t0 = u0 - u3, t1 = u1 - u2;
    y[0] = A0 * (s0 + s1);
    y[4] = A4 * (s0 - s1);
    y[2] = fmaf(A2, t0,  A6 * t1);
    y[6] = fmaf(A6, t0, -A2 * t1);
    y[1] = fmaf(A1, w0, fmaf( A3, w1, fmaf( A5, w2,  A7 * w3)));
    y[3] = fmaf(A3, w0, fmaf(-A7, w1, fmaf(-A1, w2, -A5 * w3)));
    y[5] = fmaf(A5, w0, fmaf(-A1, w1, fmaf( A7, w2,  A3 * w3)));
    y[7] = fmaf(A7, w0, fmaf(-A5, w1, fmaf( A3, w2, -A1 * w3)));
}

// 8-point inverse (x = M^T y), same butterfly structure reversed.  36 ops.
__device__ __forceinline__ void idct8(const float y[8], float x[8]) {
    const float sa = fmaf( A4, y[4], A0 * y[0]);
    const float sb = fmaf(-A4, y[4], A0 * y[0]);
    const float c0 = fmaf( A2, y[2],  A6 * y[6]);
    const float c1 = fmaf( A6, y[2], -A2 * y[6]);
    const float e0 = sa + c0, e3 = sa - c0;
    const float e1 = sb + c1, e2 = sb - c1;
    const float o0 = fmaf(A1, y[1], fmaf( A3, y[3], fmaf( A5, y[5],  A7 * y[7])));
    const float o1 = fmaf(A3, y[1], fmaf(-A7, y[3], fmaf(-A1, y[5], -A5 * y[7])));
    const float o2 = fmaf(A5, y[1], fmaf(-A1, y[3], fmaf( A7, y[5],  A3 * y[7])));
    const float o3 = fmaf(A7, y[1], fmaf(-A5, y[3], fmaf( A3, y[5], -A1 * y[7])));
    x[0] = e0 + o0; x[7] = e0 - o0;
    x[1] = e1 + o1; x[6] = e1 - o1;
    x[2] = e2 + o2; x[5] = e2 - o2;
    x[3] = e3 + o3; x[4] = e3 - o3;
}

// Rotated Csh column: logical (patch,within) at row, channel ocl ->
// physical column. Breaks the 8-way same-bank pattern of straight layout.
__device__ __forceinline__ int pcolrot(int blk, int row, int ocl) {
    return ((blk + row + (ocl >> 2)) & 3) << 3;
}

// ---------------------------------------------------------------------------
// Prep: WinH fp16 [352][64] (rows >=340 zero), WoutKH fp16 [64][192]
// (WoutKH[o][h] = Wout[o][h], h>=170 zero).
// ---------------------------------------------------------------------------
__global__ __launch_bounds__(256) void kprep(const float* __restrict__ Win,
                                             const float* __restrict__ Wout,
                                             _Float16* __restrict__ WinH,
                                             _Float16* __restrict__ WoutKH)
{
    const int i = blockIdx.x * 256 + threadIdx.x;
    if (i < 352 * 64) WinH[i] = (i < C2 * 64) ? (_Float16)Win[i] : (_Float16)0.f;
    if (i < 64 * 192) {
        const int o = i / 192, h = i - o * 192;
        WoutKH[i] = (h < HID) ? (_Float16)Wout[o * HID + h] : (_Float16)0.f;
    }
}

// ---------------------------------------------------------------------------
// Kernel A (r4 restructure): forward 2D DCT moved to the cin side (commutes
// with the 1x1 projection).  (byte-identical to r4/r8 — untouched)
// ---------------------------------------------------------------------------
__global__ __launch_bounds__(256) void kA(
    const float* __restrict__ x,        // [nb][64][256][256]
    const _Float16* __restrict__ WinH,  // [352][64] fp16 (zero-padded)
    const float* __restrict__ quant,    // [340][8][8]
    _Float16* __restrict__ yr)          // [nb][340][NP] fp16
{
    const int tid  = threadIdx.x;
    const int tile = blockIdx.x;
    const int bb   = blockIdx.y;
    const int ty = tile >> 3, tx = tile & 7;     // ty 0..31, tx 0..7
    const int y0 = ty * 8,    x0 = tx * 32;
    const int wv = tid >> 6;
    const int l15 = tid & 15, quad = (tid & 63) >> 4;

    __shared__ float csh[32 * 264];     // 33792 B

    // Zero yr's per-channel pad region for this batch (tile 0 blocks only).
    if (tile == 0) {
        const f16x8 z = {(_Float16)0.f,(_Float16)0.f,(_Float16)0.f,(_Float16)0.f,
                         (_Float16)0.f,(_Float16)0.f,(_Float16)0.f,(_Float16)0.f};
#pragma unroll 1
        for (int it = 0; it < 11; ++it) {
            const int idx = tid + it * 256;            // 2720 groups of 8
            if (idx < C2 * 8) {
                const int oc = idx >> 3, sub = idx & 7;
                *(f16x8*)&yr[(size_t)(bb * C2 + oc) * NP + NPIX + sub * 8] = z;
            }
        }
    }

    // Transform-phase roles
    const int ch  = tid >> 5;             // 0..7
    const int pat = (tid >> 3) & 3;       // 0..3 (horizontal patch)
    const int lan = tid & 7;              // 0..7

    const float* xb = x + (size_t)bb * (CIN * NPIX);

    // ---- Prologue: 2D DCT of x -> fp16 A-fragments (2 halves of 32 cin) ----
    f16x8 af0[4], af1[4];
#pragma unroll
    for (int hh = 0; hh < 2; ++hh) {
#pragma unroll
        for (int di = 0; di < 4; ++di) {
            const int ci = ch + 8 * di;
            const float* gp = xb + (size_t)(hh * 32 + ci) * NPIX
                              + (y0 + lan) * HW + x0 + pat * 8;
            float v[8], o[8];
            *(f32x4*)&v[0] = *(const f32x4*)gp;
            *(f32x4*)&v[4] = *(const f32x4*)(gp + 4);
            dct8(v, o);
            float* rowp = &csh[ci * 264 + lan * 32 + pcolrot(pat, lan, ci)];
            *(f32x4*)rowp       = *(const f32x4*)&o[0];
            *(f32x4*)(rowp + 4) = *(const f32x4*)&o[4];
        }
        __syncthreads();
#pragma unroll
        for (int di = 0; di < 4; ++di) {
            const int ci = ch + 8 * di;
            float v[8], o[8];
#pragma unroll
            for (int i = 0; i < 8; ++i)
                v[i] = csh[ci * 264 + i * 32 + pcolrot(pat, i, ci) + lan];
            dct8(v, o);
#pragma unroll
            for (int i = 0; i < 8; ++i)
                csh[ci * 264 + i * 32 + pcolrot(pat, i, ci) + lan] = o[i];
        }
        __syncthreads();
#pragma unroll
        for (int tt = 0; tt < 4; ++tt) {
            const int apx = (wv * 4 + tt) * 16 + l15;
            const int prw = apx >> 5;             // vertical freq i (0..7)
            const int pc  = apx & 31;
            const int pp  = pc >> 3, pl = pc & 7; // patch, horizontal freq j
            union { _Float16 h[8]; f16x8 v; } pk;
#pragma unroll
            for (int e = 0; e < 8; ++e) {
                const int ci = quad * 8 + e;
                pk.h[e] = (_Float16)csh[ci * 264 + prw * 32
                                        + pcolrot(pp, prw, ci) + pl];
            }
            if (hh == 0) af0[tt] = pk.v; else af1[tt] = pk.v;
        }
        __syncthreads();
    }

#pragma unroll 1
    for (int sc = 0; sc < 11; ++sc) {
        const int oc0 = sc * 32;

        // ---- MFMA projection (DCT domain) + fused quant -> csh ----
#pragma unroll
        for (int g2 = 0; g2 < 2; ++g2) {
            const int ocb = oc0 + g2 * 16 + l15;           // WinH zero-padded
            const f16x8 b0 = *(const f16x8*)(WinH + ocb * 64 + quad * 8);
            const f16x8 b1 = *(const f16x8*)(WinH + ocb * 64 + 32 + quad * 8);
            const int ocl = g2 * 16 + l15;
            int ocq = oc0 + ocl; if (ocq > C2 - 1) ocq = C2 - 1;
            const float* qbase = quant + ocq * 64 + (quad & 1) * 4;
#pragma unroll
            for (int tt = 0; tt < 4; ++tt) {
                const int tile16 = wv * 4 + tt;
                f32x4 acc = {0.f, 0.f, 0.f, 0.f};
                acc = __builtin_amdgcn_mfma_f32_16x16x32_f16(af0[tt], b0, acc, 0, 0, 0);
                acc = __builtin_amdgcn_mfma_f32_16x16x32_f16(af1[tt], b1, acc, 0, 0, 0);
                const int prow = tile16 >> 1;                  // freq row i
                const int blk  = ((tile16 & 1) << 1) | (quad >> 1);
                const f32x4 qv = *(const f32x4*)(qbase + prow * 8);
                acc *= qv;
                *(f32x4*)&csh[ocl * 264 + prow * 32 + pcolrot(blk, prow, ocl)
                              + (quad & 1) * 4] = acc;
            }
        }
        __syncthreads();

        // ---- Col-IDCT (vertical) ----
#pragma unroll
        for (int di = 0; di < 4; ++di) {
            const int ocl = ch + 8 * di;
            float v[8], e8[8];
#pragma unroll
            for (int i = 0; i < 8; ++i)
                v[i] = csh[ocl * 264 + i * 32 + pcolrot(pat, i, ocl) + lan];
            idct8(v, e8);
#pragma unroll
            for (int i = 0; i < 8; ++i)
                csh[ocl * 264 + i * 32 + pcolrot(pat, i, ocl) + lan] = e8[i];
        }
        __syncthreads();

        // ---- Row-IDCT -> global fp16, 64B full sectors ----
#pragma unroll
        for (int di = 0; di < 4; ++di) {
            const int ocl = ch + 8 * di;
            const int oc  = oc0 + ocl;
            const float* rowp = &csh[ocl * 264 + lan * 32 + pcolrot(pat, lan, ocl)];
            float v[8], e8[8];
            *(f32x4*)&v[0] = *(const f32x4*)rowp;
            *(f32x4*)&v[4] = *(const f32x4*)(rowp + 4);
            idct8(v, e8);
            union { _Float16 h[8]; f16x8 f; } u;
#pragma unroll
            for (int q = 0; q < 8; ++q) u.h[q] = (_Float16)e8[q];
            if (oc < C2) {
                f16x8* dst = (f16x8*)(yr + (size_t)(bb * C2 + oc) * NP
                                      + (y0 + lan) * HW + x0 + pat * 8);
                *dst = u.f;
            }
        }
        __syncthreads();
    }
}

// ---------------------------------------------------------------------------
// Kernel B (r10): fused conv+gelu+GEMM as in r5, but 512-thread blocks
// (8 waves).  Each wave: 4 h/chunk for conv (was 8) and 2 MFMA px-tiles
// (was 4) -> acc 32 VGPR (was 64) -> ~107 total regs -> 2 blocks/CU =
// 16 waves/CU (2x occupancy).  g-tile byte image identical to r5: wave
// wv=2q+r writes its 4-h half (8B) at slot (q^(L&3))*16 + r*8; MFMA
// reader formula unchanged.  Conv math & FMA order identical to r5.
// ---------------------------------------------------------------------------
__global__ __launch_bounds__(512, 4) void kB(
    const _Float16* __restrict__ yr,      // [nb][340][NP] fp16
    const float* __restrict__ Wdw,        // [340][9]
    const _Float16* __restrict__ WoutKH,  // [64][192] fp16 (zero-padded)
    float* __restrict__ out)              // [nb][64][256][256]
{
    const int tid = threadIdx.x;                        // 0..511
    const int bb  = blockIdx.y;
    const int id  = blockIdx.x;                         // 0..255
    const int row = ((id & 7) << 5) | (id >> 3);        // XCD strip swizzle
    const int wv  = tid >> 6;                           // 0..7
    const int L   = tid & 63;                           // lane within wave
    const int l15 = tid & 15, quad = (tid & 63) >> 4;
    const int q8  = wv >> 1, r8 = wv & 1;               // h-group, half

    __shared__ union {
        _Float16 g[256 * 32];    // 16384 B: g tile for one 32-h chunk
        float    t[16 * 257];    // 16448 B: epilogue transpose
    } shm;

    // Channel-plane base, biased -16 bytes so voffsets stay non-negative.
    const char* ybase = (const char*)(yr + (size_t)bb * C2 * NP) - 16;

    // 3 vertical tap rows -> unsigned byte offsets into (plane - 16).
    unsigned boff[3];
#pragma unroll
    for (int rr = 0; rr < 3; ++rr) {
        const int trow = row + rr - 1;
        boff[rr] = ((unsigned)trow < (unsigned)HW)
                 ? (unsigned)(trow * (HW * 2) + 8 * L + 12)
                 : (unsigned)(NPIX * 2 + 16);
    }
    const float mL = (L == 0)  ? 0.f : 1.f;   // zero col -1  (element 1)
    const float mR = (L == 63) ? 0.f : 1.f;   // zero col 256 (element 6)

    f32x4 acc[2][4];   // [px-tile tt][oc-group p] — 32 VGPRs
#pragma unroll
    for (int a = 0; a < 2; ++a)
#pragma unroll
        for (int b = 0; b < 4; ++b) acc[a][b] = (f32x4){0.f, 0.f, 0.f, 0.f};

    // LDS write base: px 4L+i at byte px*64 + slot*16 + r8*8,
    // slot = q8 ^ (L&3).  8B (4 h) per px per wave.
    char* gpc = (char*)shm.g + L * 256 + ((q8 ^ (L & 3)) << 4) + r8 * 8;

#pragma unroll 1
    for (int chunk = 0; chunk < 6; ++chunk) {
        const int hc = chunk * 32;

        union { _Float16 h[4]; f16x4v v; } pk0, pk1, pk2, pk3;
#pragma unroll
        for (int j = 0; j < 4; ++j) {
            const int h = hc + wv * 4 + j;          // wave-uniform
            float gg0 = 0.f, gg1 = 0.f, gg2 = 0.f, gg3 = 0.f;
            if (h < HID) {
                const char* p1 = ybase + (size_t)h * (NP * 2);
                const char* p2 = p1 + (size_t)HID * (NP * 2);
                const float* w1 = Wdw + h * 9;
                const float* w2 = w1 + HID * 9;
                float s1[4] = {0.f, 0.f, 0.f, 0.f};
                float s2[4] = {0.f, 0.f, 0.f, 0.f};
#pragma unroll
                for (int rr = 0; rr < 3; ++rr) {
                    f16x8 a1, a2;
                    __builtin_memcpy(&a1, p1 + boff[rr], 16);
                    __builtin_memcpy(&a2, p2 + boff[rr], 16);
                    float v1[8], v2[8];
#pragma unroll
                    for (int e = 1; e <= 6; ++e) {
                        v1[e] = (float)a1[e];
                        v2[e] = (float)a2[e];
                    }
                    v1[1] *= mL; v2[1] *= mL;
                    v1[6] *= mR; v2[6] *= mR;
                    const float wa = w1[rr*3+0], wb = w1[rr*3+1], wc = w1[rr*3+2];
                    const float wd = w2[rr*3+0], we = w2[rr*3+1], wf = w2[rr*3+2];
#pragma unroll
                    for (int i = 0; i < 4; ++i) {
                        s1[i] = fmaf(v1[i+1], wa, s1[i]);
                        s1[i] = fmaf(v1[i+2], wb, s1[i]);
                        s1[i] = fmaf(v1[i+3], wc, s1[i]);
                        s2[i] = fmaf(v2[i+1], wd, s2[i]);
                        s2[i] = fmaf(v2[i+2], we, s2[i]);
                        s2[i] = fmaf(v2[i+3], wf, s2[i]);
                    }
                }
                const float KC = 0.70710678118654752f;
                gg0 = 0.5f * s1[0] * (1.f + erff(s1[0] * KC)) * s2[0];
                gg1 = 0.5f * s1[1] * (1.f + erff(s1[1] * KC)) * s2[1];
                gg2 = 0.5f * s1[2] * (1.f + erff(s1[2] * KC)) * s2[2];
                gg3 = 0.5f * s1[3] * (1.f + erff(s1[3] * KC)) * s2[3];
            }
            pk0.h[j] = (_Float16)gg0;
            pk1.h[j] = (_Float16)gg1;
            pk2.h[j] = (_Float16)gg2;
            pk3.h[j] = (_Float16)gg3;
        }
        *(f16x4v*)(gpc      ) = pk0.v;   // px 4L+0
        *(f16x4v*)(gpc +  64) = pk1.v;   // px 4L+1
        *(f16x4v*)(gpc + 128) = pk2.v;   // px 4L+2
        *(f16x4v*)(gpc + 192) = pk3.v;   // px 4L+3
        __syncthreads();

        // ---- MFMA: acc[px, oc] += g[px, h32] * WoutKH[oc][h32] ----
#pragma unroll
        for (int tt = 0; tt < 2; ++tt) {
            const int apx = (wv * 2 + tt) * 16 + l15;
            const f16x8 a = *(const f16x8*)((const char*)shm.g + apx * 64
                              + ((quad ^ ((l15 >> 2) & 3)) << 4));
#pragma unroll
            for (int p = 0; p < 4; ++p) {
                const f16x8 b = *(const f16x8*)(WoutKH + (p * 16 + l15) * 192 + hc + quad * 8);
                acc[tt][p] = __builtin_amdgcn_mfma_f32_16x16x32_f16(a, b, acc[tt][p], 0, 0, 0);
            }
        }
        __syncthreads();
    }

    // ---- Epilogue: LDS transpose -> coalesced stores (static acc idx) ----
    const int col  = tid & 255;
    const int half = tid >> 8;
    float* ob = out + (size_t)bb * CIN * NPIX + row * HW + col;
#pragma unroll
    for (int p = 0; p < 4; ++p) {
#pragma unroll
        for (int tt = 0; tt < 2; ++tt) {
            const int px = (wv * 2 + tt) * 16 + quad * 4;
#pragma unroll
            for (int reg = 0; reg < 4; ++reg)
                shm.t[l15 * 257 + px + reg] = acc[tt][p][reg];
        }
        __syncthreads();
#pragma unroll
        for (int o2h = 0; o2h < 8; ++o2h) {
            const int o2 = half * 8 + o2h;
            ob[(size_t)(p * 16 + o2) * NPIX] = shm.t[o2 * 257 + col];
        }
        __syncthreads();
    }
}

extern "C" void kernel_launch(void* const* d_in, const int* in_sizes, int n_in,
                              void* d_out, int out_size, void* d_ws, size_t ws_size,
                              hipStream_t stream)
{
    const float* x     = (const float*)d_in[0];
    const float* Win   = (const float*)d_in[1];
    const float* Wdw   = (const float*)d_in[2];
    const float* quant = (const float*)d_in[3];
    const float* Wout  = (const float*)d_in[4];
    float* out = (float*)d_out;

    // ws: WinH [0,45056) ; WoutKH [45056,69632) ; yr at 69632 (16B aligned).
    _Float16* WinH   = (_Float16*)d_ws;
    _Float16* WoutKH = (_Float16*)((char*)d_ws + 45056);
    _Float16* yrbuf  = (_Float16*)((char*)d_ws + 69632);

    const size_t perBatch = (size_t)C2 * NP * sizeof(_Float16);  // 44.6 MB
    const size_t head = 69632;
    const size_t avail = ws_size > head ? ws_size - head : 0;
    int nb = 1;
    if (avail >= 4 * perBatch)      nb = 4;
    else if (avail >= 2 * perBatch) nb = 2;

    kprep<<<88, 256, 0, stream>>>(Win, Wout, WinH, WoutKH);

    for (int b0 = 0; b0 < 4; b0 += nb) {
        dim3 grid(256, nb);
        kA<<<grid, 256, 0, stream>>>(x + (size_t)b0 * CIN * NPIX, WinH, quant, yrbuf);
        kB<<<grid, 512, 0, stream>>>(yrbuf, Wdw, WoutKH, out + (size_t)b0 * CIN * NPIX);
    }
}

// Round 12
// 309.486 us; speedup vs baseline: 1.1738x; 1.0158x over previous
//
#include <hip/hip_runtime.h>
#include <cmath>

#define HW   256
#define NPIX 65536       // 256*256
#define NP   65600       // padded channel stride for yr (64-entry zero pad)
#define CIN  64
#define C2   340
#define HID  170

typedef _Float16 f16x8 __attribute__((ext_vector_type(8)));
typedef float    f32x4 __attribute__((ext_vector_type(4)));
typedef unsigned int u32;

// Orthonormal DCT-II basis for n=8 as compile-time constants.
#define A0 0.35355339059327373f
#define A1 0.49039264020161522f
#define A2 0.46193976625564337f
#define A3 0.41573480615127262f
#define A4 0.35355339059327379f
#define A5 0.27778511650980114f
#define A6 0.19134171618254492f
#define A7 0.09754516100806417f

// 8-point orthonormal DCT-II via even/odd butterfly: y = M v.  36 ops vs 64.
__device__ __forceinline__ void dct8(const float v[8], float y[8]) {
    const float u0 = v[0] + v[7], u1 = v[1] + v[6];
    const float u2 = v[2] + v[5], u3 = v[3] + v[4];
    const float w0 = v[0] - v[7], w1 = v[1] - v[6];
    const float w2 = v[2] - v[5], w3 = v[3] - v[4];
    const float s0 = u0 + u3, s1 = u1 + u2;
    const float t0 = u0 - u3, t1 = u1 - u2;
    y[0] = A0 * (s0 + s1);
    y[4] = A4 * (s0 - s1);
    y[2] = fmaf(A2, t0,  A6 * t1);
    y[6] = fmaf(A6, t0, -A2 * t1);
    y[1] = fmaf(A1, w0, fmaf( A3, w1, fmaf( A5, w2,  A7 * w3)));
    y[3] = fmaf(A3, w0, fmaf(-A7, w1, fmaf(-A1, w2, -A5 * w3)));
    y[5] = fmaf(A5, w0, fmaf(-A1, w1, fmaf( A7, w2,  A3 * w3)));
    y[7] = fmaf(A7, w0, fmaf(-A5, w1, fmaf( A3, w2, -A1 * w3)));
}

// 8-point inverse (x = M^T y), same butterfly structure reversed.  36 ops.
__device__ __forceinline__ void idct8(const float y[8], float x[8]) {
    const float sa = fmaf( A4, y[4], A0 * y[0]);
    const float sb = fmaf(-A4, y[4], A0 * y[0]);
    const float c0 = fmaf( A2, y[2],  A6 * y[6]);
    const float c1 = fmaf( A6, y[2], -A2 * y[6]);
    const float e0 = sa + c0, e3 = sa - c0;
    const float e1 = sb + c1, e2 = sb - c1;
    const float o0 = fmaf(A1, y[1], fmaf( A3, y[3], fmaf( A5, y[5],  A7 * y[7])));
    const float o1 = fmaf(A3, y[1], fmaf(-A7, y[3], fmaf(-A1, y[5], -A5 * y[7])));
    const float o2 = fmaf(A5, y[1], fmaf(-A1, y[3], fmaf( A7, y[5],  A3 * y[7])));
    const float o3 = fmaf(A7, y[1], fmaf(-A5, y[3], fmaf( A3, y[5], -A1 * y[7])));
    x[0] = e0 + o0; x[7] = e0 - o0;
    x[1] = e1 + o1; x[6] = e1 - o1;
    x[2] = e2 + o2; x[5] = e2 - o2;
    x[3] = e3 + o3; x[4] = e3 - o3;
}

// Rotated Csh column: logical (patch,within) at row, channel ocl ->
// physical column. Breaks the 8-way same-bank pattern of straight layout.
__device__ __forceinline__ int pcolrot(int blk, int row, int ocl) {
    return ((blk + row + (ocl >> 2)) & 3) << 3;
}

// ---------------------------------------------------------------------------
// Prep: WinH fp16 [352][64] (rows >=340 zero), WoutKH fp16 [64][192]
// (WoutKH[o][h] = Wout[o][h], h>=170 zero).
// ---------------------------------------------------------------------------
__global__ __launch_bounds__(256) void kprep(const float* __restrict__ Win,
                                             const float* __restrict__ Wout,
                                             _Float16* __restrict__ WinH,
                                             _Float16* __restrict__ WoutKH)
{
    const int i = blockIdx.x * 256 + threadIdx.x;
    if (i < 352 * 64) WinH[i] = (i < C2 * 64) ? (_Float16)Win[i] : (_Float16)0.f;
    if (i < 64 * 192) {
        const int o = i / 192, h = i - o * 192;
        WoutKH[i] = (h < HID) ? (_Float16)Wout[o * HID + h] : (_Float16)0.f;
    }
}

// ---------------------------------------------------------------------------
// Kernel A (r4 restructure): forward 2D DCT moved to the cin side (commutes
// with the 1x1 projection).  Prologue: per-patch 2D DCT of x (64 cin, f32,
// via csh, 2 halves of 32) -> fp16 MFMA A-fragments in registers.  Chunk
// loop (11 x 32 oc): MFMA -> DCT-domain Y, fused quant mul, csh store ->
// col-IDCT -> row-IDCT -> yr.  3 barriers/chunk.
// ---------------------------------------------------------------------------
__global__ __launch_bounds__(256) void kA(
    const float* __restrict__ x,        // [nb][64][256][256]
    const _Float16* __restrict__ WinH,  // [352][64] fp16 (zero-padded)
    const float* __restrict__ quant,    // [340][8][8]
    _Float16* __restrict__ yr)          // [nb][340][NP] fp16
{
    const int tid  = threadIdx.x;
    const int tile = blockIdx.x;
    const int bb   = blockIdx.y;
    const int ty = tile >> 3, tx = tile & 7;     // ty 0..31, tx 0..7
    const int y0 = ty * 8,    x0 = tx * 32;
    const int wv = tid >> 6;
    const int l15 = tid & 15, quad = (tid & 63) >> 4;

    __shared__ float csh[32 * 264];     // 33792 B

    // Zero yr's per-channel pad region for this batch (tile 0 blocks only).
    if (tile == 0) {
        const f16x8 z = {(_Float16)0.f,(_Float16)0.f,(_Float16)0.f,(_Float16)0.f,
                         (_Float16)0.f,(_Float16)0.f,(_Float16)0.f,(_Float16)0.f};
#pragma unroll 1
        for (int it = 0; it < 11; ++it) {
            const int idx = tid + it * 256;            // 2720 groups of 8
            if (idx < C2 * 8) {
                const int oc = idx >> 3, sub = idx & 7;
                *(f16x8*)&yr[(size_t)(bb * C2 + oc) * NP + NPIX + sub * 8] = z;
            }
        }
    }

    // Transform-phase roles
    const int ch  = tid >> 5;             // 0..7
    const int pat = (tid >> 3) & 3;       // 0..3 (horizontal patch)
    const int lan = tid & 7;              // 0..7

    const float* xb = x + (size_t)bb * (CIN * NPIX);

    // ---- Prologue: 2D DCT of x -> fp16 A-fragments (2 halves of 32 cin) ----
    f16x8 af0[4], af1[4];
#pragma unroll
    for (int hh = 0; hh < 2; ++hh) {
#pragma unroll
        for (int di = 0; di < 4; ++di) {
            const int ci = ch + 8 * di;
            const float* gp = xb + (size_t)(hh * 32 + ci) * NPIX
                              + (y0 + lan) * HW + x0 + pat * 8;
            float v[8], o[8];
            *(f32x4*)&v[0] = *(const f32x4*)gp;
            *(f32x4*)&v[4] = *(const f32x4*)(gp + 4);
            dct8(v, o);
            float* rowp = &csh[ci * 264 + lan * 32 + pcolrot(pat, lan, ci)];
            *(f32x4*)rowp       = *(const f32x4*)&o[0];
            *(f32x4*)(rowp + 4) = *(const f32x4*)&o[4];
        }
        __syncthreads();
#pragma unroll
        for (int di = 0; di < 4; ++di) {
            const int ci = ch + 8 * di;
            float v[8], o[8];
#pragma unroll
            for (int i = 0; i < 8; ++i)
                v[i] = csh[ci * 264 + i * 32 + pcolrot(pat, i, ci) + lan];
            dct8(v, o);
#pragma unroll
            for (int i = 0; i < 8; ++i)
                csh[ci * 264 + i * 32 + pcolrot(pat, i, ci) + lan] = o[i];
        }
        __syncthreads();
#pragma unroll
        for (int tt = 0; tt < 4; ++tt) {
            const int apx = (wv * 4 + tt) * 16 + l15;
            const int prw = apx >> 5;             // vertical freq i (0..7)
            const int pc  = apx & 31;
            const int pp  = pc >> 3, pl = pc & 7; // patch, horizontal freq j
            union { _Float16 h[8]; f16x8 v; } pk;
#pragma unroll
            for (int e = 0; e < 8; ++e) {
                const int ci = quad * 8 + e;
                pk.h[e] = (_Float16)csh[ci * 264 + prw * 32
                                        + pcolrot(pp, prw, ci) + pl];
            }
            if (hh == 0) af0[tt] = pk.v; else af1[tt] = pk.v;
        }
        __syncthreads();
    }

#pragma unroll 1
    for (int sc = 0; sc < 11; ++sc) {
        const int oc0 = sc * 32;

        // ---- MFMA projection (DCT domain) + fused quant -> csh ----
#pragma unroll
        for (int g2 = 0; g2 < 2; ++g2) {
            const int ocb = oc0 + g2 * 16 + l15;           // WinH zero-padded
            const f16x8 b0 = *(const f16x8*)(WinH + ocb * 64 + quad * 8);
            const f16x8 b1 = *(const f16x8*)(WinH + ocb * 64 + 32 + quad * 8);
            const int ocl = g2 * 16 + l15;
            int ocq = oc0 + ocl; if (ocq > C2 - 1) ocq = C2 - 1;
            const float* qbase = quant + ocq * 64 + (quad & 1) * 4;
#pragma unroll
            for (int tt = 0; tt < 4; ++tt) {
                const int tile16 = wv * 4 + tt;
                f32x4 acc = {0.f, 0.f, 0.f, 0.f};
                acc = __builtin_amdgcn_mfma_f32_16x16x32_f16(af0[tt], b0, acc, 0, 0, 0);
                acc = __builtin_amdgcn_mfma_f32_16x16x32_f16(af1[tt], b1, acc, 0, 0, 0);
                const int prow = tile16 >> 1;                  // freq row i
                const int blk  = ((tile16 & 1) << 1) | (quad >> 1);
                const f32x4 qv = *(const f32x4*)(qbase + prow * 8);
                acc *= qv;
                *(f32x4*)&csh[ocl * 264 + prow * 32 + pcolrot(blk, prow, ocl)
                              + (quad & 1) * 4] = acc;
            }
        }
        __syncthreads();

        // ---- Col-IDCT (vertical) ----
#pragma unroll
        for (int di = 0; di < 4; ++di) {
            const int ocl = ch + 8 * di;
            float v[8], e8[8];
#pragma unroll
            for (int i = 0; i < 8; ++i)
                v[i] = csh[ocl * 264 + i * 32 + pcolrot(pat, i, ocl) + lan];
            idct8(v, e8);
#pragma unroll
            for (int i = 0; i < 8; ++i)
                csh[ocl * 264 + i * 32 + pcolrot(pat, i, ocl) + lan] = e8[i];
        }
        __syncthreads();

        // ---- Row-IDCT -> global fp16, 64B full sectors ----
#pragma unroll
        for (int di = 0; di < 4; ++di) {
            const int ocl = ch + 8 * di;
            const int oc  = oc0 + ocl;
            const float* rowp = &csh[ocl * 264 + lan * 32 + pcolrot(pat, lan, ocl)];
            float v[8], e8[8];
            *(f32x4*)&v[0] = *(const f32x4*)rowp;
            *(f32x4*)&v[4] = *(const f32x4*)(rowp + 4);
            idct8(v, e8);
            union { _Float16 h[8]; f16x8 f; } u;
#pragma unroll
            for (int q = 0; q < 8; ++q) u.h[q] = (_Float16)e8[q];
            if (oc < C2) {
                f16x8* dst = (f16x8*)(yr + (size_t)(bb * C2 + oc) * NP
                                      + (y0 + lan) * HW + x0 + pat * 8);
                *dst = u.f;
            }
        }
        __syncthreads();
    }
}

// ---------------------------------------------------------------------------
// Kernel B: depthwise 3x3 + exact gelu gate (VALU) + project_out (MFMA).
// Proven r5/r8 form: 256 threads, 4 waves, LDS g-tile, exact erff.
// (r11's A&S gelu poly failed correctness 2.9e-3 — reverted.  r6/r7/r9/r10
// structural probes all regressed: this schedule is the local optimum.)
// ---------------------------------------------------------------------------
__global__ __launch_bounds__(256, 2) void kB(
    const _Float16* __restrict__ yr,      // [nb][340][NP] fp16
    const float* __restrict__ Wdw,        // [340][9]
    const _Float16* __restrict__ WoutKH,  // [64][192] fp16 (zero-padded)
    float* __restrict__ out)              // [nb][64][256][256]
{
    const int tid = threadIdx.x;
    const int bb  = blockIdx.y;
    const int id  = blockIdx.x;                         // 0..255
    const int row = ((id & 7) << 5) | (id >> 3);        // XCD strip swizzle
    const int wv  = tid >> 6;
    const int L   = tid & 63;                           // lane within wave
    const int l15 = tid & 15, quad = (tid & 63) >> 4;

    __shared__ union {
        _Float16 g[256 * 32];    // 16384 B: g tile for one 32-h chunk
        float    t[16 * 257];    // 16448 B: epilogue transpose
    } shm;

    // Channel-plane base, biased -16 bytes so voffsets stay non-negative.
    const char* ybase = (const char*)(yr + (size_t)bb * C2 * NP) - 16;

    // 3 vertical tap rows -> unsigned byte offsets into (plane - 16).
    unsigned boff[3];
#pragma unroll
    for (int rr = 0; rr < 3; ++rr) {
        const int trow = row + rr - 1;
        boff[rr] = ((unsigned)trow < (unsigned)HW)
                 ? (unsigned)(trow * (HW * 2) + 8 * L + 12)
                 : (unsigned)(NPIX * 2 + 16);
    }
    const float mL = (L == 0)  ? 0.f : 1.f;   // zero col -1  (element 1)
    const float mR = (L == 63) ? 0.f : 1.f;   // zero col 256 (element 6)

    f32x4 acc[4][4];   // [px-tile tt][oc-group p]
#pragma unroll
    for (int a = 0; a < 4; ++a)
#pragma unroll
        for (int b = 0; b < 4; ++b) acc[a][b] = (f32x4){0.f, 0.f, 0.f, 0.f};

    // LDS write base for this lane's 4 px (px = 4L+i at byte px*64 + slot*16,
    // slot = wv ^ (L&3)); stores at +0/64/128/192.
    char* gpc = (char*)shm.g + L * 256 + ((wv ^ (L & 3)) << 4);

#pragma unroll 1
    for (int chunk = 0; chunk < 6; ++chunk) {
        const int hc = chunk * 32;

        union { _Float16 h[8]; f16x8 v; } pk0, pk1, pk2, pk3;
#pragma unroll
        for (int j = 0; j < 8; ++j) {
            const int h = hc + wv * 8 + j;          // wave-uniform
            float gg0 = 0.f, gg1 = 0.f, gg2 = 0.f, gg3 = 0.f;
            if (h < HID) {
                const char* p1 = ybase + (size_t)h * (NP * 2);
                const char* p2 = p1 + (size_t)HID * (NP * 2);
                const float* w1 = Wdw + h * 9;
                const float* w2 = w1 + HID * 9;
                float s1[4] = {0.f, 0.f, 0.f, 0.f};
                float s2[4] = {0.f, 0.f, 0.f, 0.f};
#pragma unroll
                for (int rr = 0; rr < 3; ++rr) {
                    f16x8 a1, a2;
                    __builtin_memcpy(&a1, p1 + boff[rr], 16);
                    __builtin_memcpy(&a2, p2 + boff[rr], 16);
                    float v1[8], v2[8];
#pragma unroll
                    for (int e = 1; e <= 6; ++e) {
                        v1[e] = (float)a1[e];
                        v2[e] = (float)a2[e];
                    }
                    v1[1] *= mL; v2[1] *= mL;
                    v1[6] *= mR; v2[6] *= mR;
                    const float wa = w1[rr*3+0], wb = w1[rr*3+1], wc = w1[rr*3+2];
                    const float wd = w2[rr*3+0], we = w2[rr*3+1], wf = w2[rr*3+2];
#pragma unroll
                    for (int i = 0; i < 4; ++i) {
                        s1[i] = fmaf(v1[i+1], wa, s1[i]);
                        s1[i] = fmaf(v1[i+2], wb, s1[i]);
                        s1[i] = fmaf(v1[i+3], wc, s1[i]);
                        s2[i] = fmaf(v2[i+1], wd, s2[i]);
                        s2[i] = fmaf(v2[i+2], we, s2[i]);
                        s2[i] = fmaf(v2[i+3], wf, s2[i]);
                    }
                }
                const float KC = 0.70710678118654752f;
                gg0 = 0.5f * s1[0] * (1.f + erff(s1[0] * KC)) * s2[0];
                gg1 = 0.5f * s1[1] * (1.f + erff(s1[1] * KC)) * s2[1];
                gg2 = 0.5f * s1[2] * (1.f + erff(s1[2] * KC)) * s2[2];
                gg3 = 0.5f * s1[3] * (1.f + erff(s1[3] * KC)) * s2[3];
            }
            pk0.h[j] = (_Float16)gg0;
            pk1.h[j] = (_Float16)gg1;
            pk2.h[j] = (_Float16)gg2;
            pk3.h[j] = (_Float16)gg3;
        }
        *(f16x8*)(gpc      ) = pk0.v;   // px 4L+0
        *(f16x8*)(gpc +  64) = pk1.v;   // px 4L+1
        *(f16x8*)(gpc + 128) = pk2.v;   // px 4L+2
        *(f16x8*)(gpc + 192) = pk3.v;   // px 4L+3
        __syncthreads();

        // ---- MFMA: acc[px, oc] += g[px, h32] * WoutKH[oc][h32] ----
#pragma unroll
        for (int tt = 0; tt < 4; ++tt) {
            const int apx = (wv * 4 + tt) * 16 + l15;
            const f16x8 a = *(const f16x8*)((const char*)shm.g + apx * 64
                              + ((quad ^ ((l15 >> 2) & 3)) << 4));
#pragma unroll
            for (int p = 0; p < 4; ++p) {
                const f16x8 b = *(const f16x8*)(WoutKH + (p * 16 + l15) * 192 + hc + quad * 8);
                acc[tt][p] = __builtin_amdgcn_mfma_f32_16x16x32_f16(a, b, acc[tt][p], 0, 0, 0);
            }
        }
        __syncthreads();
    }

    // ---- Epilogue: LDS transpose -> coalesced stores.  FULLY unrolled so
    //      acc indexing stays static (never scratch). ----
    float* ob = out + (size_t)bb * CIN * NPIX + row * HW + tid;
#pragma unroll
    for (int p = 0; p < 4; ++p) {
#pragma unroll
        for (int tt = 0; tt < 4; ++tt) {
            const int px = (wv * 4 + tt) * 16 + quad * 4;
#pragma unroll
            for (int reg = 0; reg < 4; ++reg)
                shm.t[l15 * 257 + px + reg] = acc[tt][p][reg];
        }
        __syncthreads();
#pragma unroll
        for (int o2 = 0; o2 < 16; ++o2)
            ob[(size_t)(p * 16 + o2) * NPIX] = shm.t[o2 * 257 + tid];
        __syncthreads();
    }
}

extern "C" void kernel_launch(void* const* d_in, const int* in_sizes, int n_in,
                              void* d_out, int out_size, void* d_ws, size_t ws_size,
                              hipStream_t stream)
{
    const float* x     = (const float*)d_in[0];
    const float* Win   = (const float*)d_in[1];
    const float* Wdw   = (const float*)d_in[2];
    const float* quant = (const float*)d_in[3];
    const float* Wout  = (const float*)d_in[4];
    float* out = (float*)d_out;

    // ws: WinH [0,45056) ; WoutKH [45056,69632) ; yr at 69632 (16B aligned).
    _Float16* WinH   = (_Float16*)d_ws;
    _Float16* WoutKH = (_Float16*)((char*)d_ws + 45056);
    _Float16* yrbuf  = (_Float16*)((char*)d_ws + 69632);

    const size_t perBatch = (size_t)C2 * NP * sizeof(_Float16);  // 44.6 MB
    const size_t head = 69632;
    const size_t avail = ws_size > head ? ws_size - head : 0;
    int nb = 1;
    if (avail >= 4 * perBatch)      nb = 4;
    else if (avail >= 2 * perBatch) nb = 2;

    kprep<<<88, 256, 0, stream>>>(Win, Wout, WinH, WoutKH);

    for (int b0 = 0; b0 < 4; b0 += nb) {
        dim3 grid(256, nb);
        kA<<<grid, 256, 0, stream>>>(x + (size_t)b0 * CIN * NPIX, WinH, quant, yrbuf);
        kB<<<grid, 256, 0, stream>>>(yrbuf, Wdw, WoutKH, out + (size_t)b0 * CIN * NPIX);
    }
}

// Round 13
// 307.582 us; speedup vs baseline: 1.1810x; 1.0062x over previous
//
#include <hip/hip_runtime.h>
#include <cmath>

#define HW   256
#define NPIX 65536       // 256*256
#define NP   65600       // padded channel stride for yr (64-entry zero pad)
#define CIN  64
#define C2   340
#define HID  170

// kA csh geometry (r12): channel stride 292 floats, row stride 36 floats.
// 292 mod 32 = 4 -> ocl spreads start banks; 36 mod 32 = 4 -> row index
// spreads; both mult of 4 -> f32x4 alignment kept.  Replaces pcolrot, whose
// 8-float rotation left every row-phase x4 on 8-aligned banks (16 of 32
// banks -> 2x serialization, the stuck 15.9M conflict counter).
#define CSTR 292
#define RSTR 36

typedef _Float16 f16x8 __attribute__((ext_vector_type(8)));
typedef float    f32x4 __attribute__((ext_vector_type(4)));
typedef unsigned int u32;

// Orthonormal DCT-II basis for n=8 as compile-time constants.
#define A0 0.35355339059327373f
#define A1 0.49039264020161522f
#define A2 0.46193976625564337f
#define A3 0.41573480615127262f
#define A4 0.35355339059327379f
#define A5 0.27778511650980114f
#define A6 0.19134171618254492f
#define A7 0.09754516100806417f

// 8-point orthonormal DCT-II via even/odd butterfly: y = M v.  36 ops vs 64.
__device__ __forceinline__ void dct8(const float v[8], float y[8]) {
    const float u0 = v[0] + v[7], u1 = v[1] + v[6];
    const float u2 = v[2] + v[5], u3 = v[3] + v[4];
    const float w0 = v[0] - v[7], w1 = v[1] - v[6];
    const float w2 = v[2] - v[5], w3 = v[3] - v[4];
    const float s0 = u0 + u3, s1 = u1 + u2;
    const float t0 = u0 - u3, t1 = u1 - u2;
    y[0] = A0 * (s0 + s1);
    y[4] = A4 * (s0 - s1);
    y[2] = fmaf(A2, t0,  A6 * t1);
    y[6] = fmaf(A6, t0, -A2 * t1);
    y[1] = fmaf(A1, w0, fmaf( A3, w1, fmaf( A5, w2,  A7 * w3)));
    y[3] = fmaf(A3, w0, fmaf(-A7, w1, fmaf(-A1, w2, -A5 * w3)));
    y[5] = fmaf(A5, w0, fmaf(-A1, w1, fmaf( A7, w2,  A3 * w3)));
    y[7] = fmaf(A7, w0, fmaf(-A5, w1, fmaf( A3, w2, -A1 * w3)));
}

// 8-point inverse (x = M^T y), same butterfly structure reversed.  36 ops.
__device__ __forceinline__ void idct8(const float y[8], float x[8]) {
    const float sa = fmaf( A4, y[4], A0 * y[0]);
    const float sb = fmaf(-A4, y[4], A0 * y[0]);
    const float c0 = fmaf( A2, y[2],  A6 * y[6]);
    const float c1 = fmaf( A6, y[2], -A2 * y[6]);
    const float e0 = sa + c0, e3 = sa - c0;
    const float e1 = sb + c1, e2 = sb - c1;
    const float o0 = fmaf(A1, y[1], fmaf( A3, y[3], fmaf( A5, y[5],  A7 * y[7])));
    const float o1 = fmaf(A3, y[1], fmaf(-A7, y[3], fmaf(-A1, y[5], -A5 * y[7])));
    const float o2 = fmaf(A5, y[1], fmaf(-A1, y[3], fmaf( A7, y[5],  A3 * y[7])));
    const float o3 = fmaf(A7, y[1], fmaf(-A5, y[3], fmaf( A3, y[5], -A1 * y[7])));
    x[0] = e0 + o0; x[7] = e0 - o0;
    x[1] = e1 + o1; x[6] = e1 - o1;
    x[2] = e2 + o2; x[5] = e2 - o2;
    x[3] = e3 + o3; x[4] = e3 - o3;
}

// ---------------------------------------------------------------------------
// Prep: WinH fp16 [352][64] (rows >=340 zero), WoutKH fp16 [64][192]
// (WoutKH[o][h] = Wout[o][h], h>=170 zero).
// ---------------------------------------------------------------------------
__global__ __launch_bounds__(256) void kprep(const float* __restrict__ Win,
                                             const float* __restrict__ Wout,
                                             _Float16* __restrict__ WinH,
                                             _Float16* __restrict__ WoutKH)
{
    const int i = blockIdx.x * 256 + threadIdx.x;
    if (i < 352 * 64) WinH[i] = (i < C2 * 64) ? (_Float16)Win[i] : (_Float16)0.f;
    if (i < 64 * 192) {
        const int o = i / 192, h = i - o * 192;
        WoutKH[i] = (h < HID) ? (_Float16)Wout[o * HID + h] : (_Float16)0.f;
    }
}

// ---------------------------------------------------------------------------
// Kernel A: forward 2D DCT on the cin side (commutes with the 1x1
// projection); chunk loop MFMA+quant -> col-IDCT -> row-IDCT -> yr.
// r12: csh layout CSTR=292/RSTR=36 (bank-spread, 16B-aligned) — pure
// address permutation vs r4; FMA order and data identical.
// ---------------------------------------------------------------------------
__global__ __launch_bounds__(256) void kA(
    const float* __restrict__ x,        // [nb][64][256][256]
    const _Float16* __restrict__ WinH,  // [352][64] fp16 (zero-padded)
    const float* __restrict__ quant,    // [340][8][8]
    _Float16* __restrict__ yr)          // [nb][340][NP] fp16
{
    const int tid  = threadIdx.x;
    const int tile = blockIdx.x;
    const int bb   = blockIdx.y;
    const int ty = tile >> 3, tx = tile & 7;     // ty 0..31, tx 0..7
    const int y0 = ty * 8,    x0 = tx * 32;
    const int wv = tid >> 6;
    const int l15 = tid & 15, quad = (tid & 63) >> 4;

    __shared__ float csh[32 * CSTR];    // 37376 B (4 blocks/CU preserved)

    // Zero yr's per-channel pad region for this batch (tile 0 blocks only).
    if (tile == 0) {
        const f16x8 z = {(_Float16)0.f,(_Float16)0.f,(_Float16)0.f,(_Float16)0.f,
                         (_Float16)0.f,(_Float16)0.f,(_Float16)0.f,(_Float16)0.f};
#pragma unroll 1
        for (int it = 0; it < 11; ++it) {
            const int idx = tid + it * 256;            // 2720 groups of 8
            if (idx < C2 * 8) {
                const int oc = idx >> 3, sub = idx & 7;
                *(f16x8*)&yr[(size_t)(bb * C2 + oc) * NP + NPIX + sub * 8] = z;
            }
        }
    }

    // Transform-phase roles
    const int ch  = tid >> 5;             // 0..7
    const int pat = (tid >> 3) & 3;       // 0..3 (horizontal patch)
    const int lan = tid & 7;              // 0..7

    const float* xb = x + (size_t)bb * (CIN * NPIX);

    // ---- Prologue: 2D DCT of x -> fp16 A-fragments (2 halves of 32 cin) ----
    f16x8 af0[4], af1[4];
#pragma unroll
    for (int hh = 0; hh < 2; ++hh) {
#pragma unroll
        for (int di = 0; di < 4; ++di) {
            const int ci = ch + 8 * di;
            const float* gp = xb + (size_t)(hh * 32 + ci) * NPIX
                              + (y0 + lan) * HW + x0 + pat * 8;
            float v[8], o[8];
            *(f32x4*)&v[0] = *(const f32x4*)gp;
            *(f32x4*)&v[4] = *(const f32x4*)(gp + 4);
            dct8(v, o);
            float* rowp = &csh[ci * CSTR + lan * RSTR + pat * 8];
            *(f32x4*)rowp       = *(const f32x4*)&o[0];
            *(f32x4*)(rowp + 4) = *(const f32x4*)&o[4];
        }
        __syncthreads();
#pragma unroll
        for (int di = 0; di < 4; ++di) {
            const int ci = ch + 8 * di;
            float v[8], o[8];
#pragma unroll
            for (int i = 0; i < 8; ++i)
                v[i] = csh[ci * CSTR + i * RSTR + pat * 8 + lan];
            dct8(v, o);
#pragma unroll
            for (int i = 0; i < 8; ++i)
                csh[ci * CSTR + i * RSTR + pat * 8 + lan] = o[i];
        }
        __syncthreads();
#pragma unroll
        for (int tt = 0; tt < 4; ++tt) {
            const int apx = (wv * 4 + tt) * 16 + l15;
            const int prw = apx >> 5;             // vertical freq i (0..7)
            const int pc  = apx & 31;
            const int pp  = pc >> 3, pl = pc & 7; // patch, horizontal freq j
            union { _Float16 h[8]; f16x8 v; } pk;
#pragma unroll
            for (int e = 0; e < 8; ++e) {
                const int ci = quad * 8 + e;
                pk.h[e] = (_Float16)csh[ci * CSTR + prw * RSTR + pp * 8 + pl];
            }
            if (hh == 0) af0[tt] = pk.v; else af1[tt] = pk.v;
        }
        __syncthreads();
    }

#pragma unroll 1
    for (int sc = 0; sc < 11; ++sc) {
        const int oc0 = sc * 32;

        // ---- MFMA projection (DCT domain) + fused quant -> csh ----
#pragma unroll
        for (int g2 = 0; g2 < 2; ++g2) {
            const int ocb = oc0 + g2 * 16 + l15;           // WinH zero-padded
            const f16x8 b0 = *(const f16x8*)(WinH + ocb * 64 + quad * 8);
            const f16x8 b1 = *(const f16x8*)(WinH + ocb * 64 + 32 + quad * 8);
            const int ocl = g2 * 16 + l15;
            int ocq = oc0 + ocl; if (ocq > C2 - 1) ocq = C2 - 1;
            const float* qbase = quant + ocq * 64 + (quad & 1) * 4;
#pragma unroll
            for (int tt = 0; tt < 4; ++tt) {
                const int tile16 = wv * 4 + tt;
                f32x4 acc = {0.f, 0.f, 0.f, 0.f};
                acc = __builtin_amdgcn_mfma_f32_16x16x32_f16(af0[tt], b0, acc, 0, 0, 0);
                acc = __builtin_amdgcn_mfma_f32_16x16x32_f16(af1[tt], b1, acc, 0, 0, 0);
                const int prow = tile16 >> 1;                  // freq row i
                const int blk  = ((tile16 & 1) << 1) | (quad >> 1);
                const f32x4 qv = *(const f32x4*)(qbase + prow * 8);
                acc *= qv;
                *(f32x4*)&csh[ocl * CSTR + prow * RSTR + blk * 8
                              + (quad & 1) * 4] = acc;
            }
        }
        __syncthreads();

        // ---- Col-IDCT (vertical) ----
#pragma unroll
        for (int di = 0; di < 4; ++di) {
            const int ocl = ch + 8 * di;
            float v[8], e8[8];
#pragma unroll
            for (int i = 0; i < 8; ++i)
                v[i] = csh[ocl * CSTR + i * RSTR + pat * 8 + lan];
            idct8(v, e8);
#pragma unroll
            for (int i = 0; i < 8; ++i)
                csh[ocl * CSTR + i * RSTR + pat * 8 + lan] = e8[i];
        }
        __syncthreads();

        // ---- Row-IDCT -> global fp16, 64B full sectors ----
#pragma unroll
        for (int di = 0; di < 4; ++di) {
            const int ocl = ch + 8 * di;
            const int oc  = oc0 + ocl;
            const float* rowp = &csh[ocl * CSTR + lan * RSTR + pat * 8];
            float v[8], e8[8];
            *(f32x4*)&v[0] = *(const f32x4*)rowp;
            *(f32x4*)&v[4] = *(const f32x4*)(rowp + 4);
            idct8(v, e8);
            union { _Float16 h[8]; f16x8 f; } u;
#pragma unroll
            for (int q = 0; q < 8; ++q) u.h[q] = (_Float16)e8[q];
            if (oc < C2) {
                f16x8* dst = (f16x8*)(yr + (size_t)(bb * C2 + oc) * NP
                                      + (y0 + lan) * HW + x0 + pat * 8);
                *dst = u.f;
            }
        }
        __syncthreads();
    }
}

// ---------------------------------------------------------------------------
// Kernel B: depthwise 3x3 + exact gelu gate (VALU) + project_out (MFMA).
// Proven r5/r8 form — byte-identical, untouched for attribution.
// ---------------------------------------------------------------------------
__global__ __launch_bounds__(256, 2) void kB(
    const _Float16* __restrict__ yr,      // [nb][340][NP] fp16
    const float* __restrict__ Wdw,        // [340][9]
    const _Float16* __restrict__ WoutKH,  // [64][192] fp16 (zero-padded)
    float* __restrict__ out)              // [nb][64][256][256]
{
    const int tid = threadIdx.x;
    const int bb  = blockIdx.y;
    const int id  = blockIdx.x;                         // 0..255
    const int row = ((id & 7) << 5) | (id >> 3);        // XCD strip swizzle
    const int wv  = tid >> 6;
    const int L   = tid & 63;                           // lane within wave
    const int l15 = tid & 15, quad = (tid & 63) >> 4;

    __shared__ union {
        _Float16 g[256 * 32];    // 16384 B: g tile for one 32-h chunk
        float    t[16 * 257];    // 16448 B: epilogue transpose
    } shm;

    // Channel-plane base, biased -16 bytes so voffsets stay non-negative.
    const char* ybase = (const char*)(yr + (size_t)bb * C2 * NP) - 16;

    // 3 vertical tap rows -> unsigned byte offsets into (plane - 16).
    unsigned boff[3];
#pragma unroll
    for (int rr = 0; rr < 3; ++rr) {
        const int trow = row + rr - 1;
        boff[rr] = ((unsigned)trow < (unsigned)HW)
                 ? (unsigned)(trow * (HW * 2) + 8 * L + 12)
                 : (unsigned)(NPIX * 2 + 16);
    }
    const float mL = (L == 0)  ? 0.f : 1.f;   // zero col -1  (element 1)
    const float mR = (L == 63) ? 0.f : 1.f;   // zero col 256 (element 6)

    f32x4 acc[4][4];   // [px-tile tt][oc-group p]
#pragma unroll
    for (int a = 0; a < 4; ++a)
#pragma unroll
        for (int b = 0; b < 4; ++b) acc[a][b] = (f32x4){0.f, 0.f, 0.f, 0.f};

    // LDS write base for this lane's 4 px (px = 4L+i at byte px*64 + slot*16,
    // slot = wv ^ (L&3)); stores at +0/64/128/192.
    char* gpc = (char*)shm.g + L * 256 + ((wv ^ (L & 3)) << 4);

#pragma unroll 1
    for (int chunk = 0; chunk < 6; ++chunk) {
        const int hc = chunk * 32;

        union { _Float16 h[8]; f16x8 v; } pk0, pk1, pk2, pk3;
#pragma unroll
        for (int j = 0; j < 8; ++j) {
            const int h = hc + wv * 8 + j;          // wave-uniform
            float gg0 = 0.f, gg1 = 0.f, gg2 = 0.f, gg3 = 0.f;
            if (h < HID) {
                const char* p1 = ybase + (size_t)h * (NP * 2);
                const char* p2 = p1 + (size_t)HID * (NP * 2);
                const float* w1 = Wdw + h * 9;
                const float* w2 = w1 + HID * 9;
                float s1[4] = {0.f, 0.f, 0.f, 0.f};
                float s2[4] = {0.f, 0.f, 0.f, 0.f};
#pragma unroll
                for (int rr = 0; rr < 3; ++rr) {
                    f16x8 a1, a2;
                    __builtin_memcpy(&a1, p1 + boff[rr], 16);
                    __builtin_memcpy(&a2, p2 + boff[rr], 16);
                    float v1[8], v2[8];
#pragma unroll
                    for (int e = 1; e <= 6; ++e) {
                        v1[e] = (float)a1[e];
                        v2[e] = (float)a2[e];
                    }
                    v1[1] *= mL; v2[1] *= mL;
                    v1[6] *= mR; v2[6] *= mR;
                    const float wa = w1[rr*3+0], wb = w1[rr*3+1], wc = w1[rr*3+2];
                    const float wd = w2[rr*3+0], we = w2[rr*3+1], wf = w2[rr*3+2];
#pragma unroll
                    for (int i = 0; i < 4; ++i) {
                        s1[i] = fmaf(v1[i+1], wa, s1[i]);
                        s1[i] = fmaf(v1[i+2], wb, s1[i]);
                        s1[i] = fmaf(v1[i+3], wc, s1[i]);
                        s2[i] = fmaf(v2[i+1], wd, s2[i]);
                        s2[i] = fmaf(v2[i+2], we, s2[i]);
                        s2[i] = fmaf(v2[i+3], wf, s2[i]);
                    }
                }
                const float KC = 0.70710678118654752f;
                gg0 = 0.5f * s1[0] * (1.f + erff(s1[0] * KC)) * s2[0];
                gg1 = 0.5f * s1[1] * (1.f + erff(s1[1] * KC)) * s2[1];
                gg2 = 0.5f * s1[2] * (1.f + erff(s1[2] * KC)) * s2[2];
                gg3 = 0.5f * s1[3] * (1.f + erff(s1[3] * KC)) * s2[3];
            }
            pk0.h[j] = (_Float16)gg0;
            pk1.h[j] = (_Float16)gg1;
            pk2.h[j] = (_Float16)gg2;
            pk3.h[j] = (_Float16)gg3;
        }
        *(f16x8*)(gpc      ) = pk0.v;   // px 4L+0
        *(f16x8*)(gpc +  64) = pk1.v;   // px 4L+1
        *(f16x8*)(gpc + 128) = pk2.v;   // px 4L+2
        *(f16x8*)(gpc + 192) = pk3.v;   // px 4L+3
        __syncthreads();

        // ---- MFMA: acc[px, oc] += g[px, h32] * WoutKH[oc][h32] ----
#pragma unroll
        for (int tt = 0; tt < 4; ++tt) {
            const int apx = (wv * 4 + tt) * 16 + l15;
            const f16x8 a = *(const f16x8*)((const char*)shm.g + apx * 64
                              + ((quad ^ ((l15 >> 2) & 3)) << 4));
#pragma unroll
            for (int p = 0; p < 4; ++p) {
                const f16x8 b = *(const f16x8*)(WoutKH + (p * 16 + l15) * 192 + hc + quad * 8);
                acc[tt][p] = __builtin_amdgcn_mfma_f32_16x16x32_f16(a, b, acc[tt][p], 0, 0, 0);
            }
        }
        __syncthreads();
    }

    // ---- Epilogue: LDS transpose -> coalesced stores.  FULLY unrolled so
    //      acc indexing stays static (never scratch). ----
    float* ob = out + (size_t)bb * CIN * NPIX + row * HW + tid;
#pragma unroll
    for (int p = 0; p < 4; ++p) {
#pragma unroll
        for (int tt = 0; tt < 4; ++tt) {
            const int px = (wv * 4 + tt) * 16 + quad * 4;
#pragma unroll
            for (int reg = 0; reg < 4; ++reg)
                shm.t[l15 * 257 + px + reg] = acc[tt][p][reg];
        }
        __syncthreads();
#pragma unroll
        for (int o2 = 0; o2 < 16; ++o2)
            ob[(size_t)(p * 16 + o2) * NPIX] = shm.t[o2 * 257 + tid];
        __syncthreads();
    }
}

extern "C" void kernel_launch(void* const* d_in, const int* in_sizes, int n_in,
                              void* d_out, int out_size, void* d_ws, size_t ws_size,
                              hipStream_t stream)
{
    const float* x     = (const float*)d_in[0];
    const float* Win   = (const float*)d_in[1];
    const float* Wdw   = (const float*)d_in[2];
    const float* quant = (const float*)d_in[3];
    const float* Wout  = (const float*)d_in[4];
    float* out = (float*)d_out;

    // ws: WinH [0,45056) ; WoutKH [45056,69632) ; yr at 69632 (16B aligned).
    _Float16* WinH   = (_Float16*)d_ws;
    _Float16* WoutKH = (_Float16*)((char*)d_ws + 45056);
    _Float16* yrbuf  = (_Float16*)((char*)d_ws + 69632);

    const size_t perBatch = (size_t)C2 * NP * sizeof(_Float16);  // 44.6 MB
    const size_t head = 69632;
    const size_t avail = ws_size > head ? ws_size - head : 0;
    int nb = 1;
    if (avail >= 4 * perBatch)      nb = 4;
    else if (avail >= 2 * perBatch) nb = 2;

    kprep<<<88, 256, 0, stream>>>(Win, Wout, WinH, WoutKH);

    for (int b0 = 0; b0 < 4; b0 += nb) {
        dim3 grid(256, nb);
        kA<<<grid, 256, 0, stream>>>(x + (size_t)b0 * CIN * NPIX, WinH, quant, yrbuf);
        kB<<<grid, 256, 0, stream>>>(yrbuf, Wdw, WoutKH, out + (size_t)b0 * CIN * NPIX);
    }
}